// Round 1
// baseline (4553.892 us; speedup 1.0000x reference)
//
#include <hip/hip_runtime.h>
#include <hip/hip_bf16.h>

#define AS1 __attribute__((address_space(1)))
#define AS3 __attribute__((address_space(3)))

typedef __bf16 bf16_t;
typedef __attribute__((ext_vector_type(8))) __bf16 bfrag;
typedef __attribute__((ext_vector_type(4))) __bf16 bf16x4;
typedef __attribute__((ext_vector_type(4))) float ffrag;

#define S_LEN 2048
#define B_DIM 16
#define H_DIM 1024
#define N3H   3072
#define M_DIM 32768  /* S*B */

__device__ __forceinline__ float sigmoidf_(float x) {
  return 1.0f / (1.0f + __expf(-x));
}
__device__ __forceinline__ float tanh_fast(float x) {
  return 2.0f / (1.0f + __expf(-2.0f * x)) - 1.0f;
}

// ---------------- embedding gather: X[s*B+b][h] = bf16(emb[x[s*B+b]][h]) ---
__global__ __launch_bounds__(256) void embed_kernel(
    const int* __restrict__ x, const float* __restrict__ emb,
    bf16_t* __restrict__ X)
{
  const int row = blockIdx.x;            // 0..32767 = s*16+b
  const int v = x[row];
  const float4* src = (const float4*)(emb + (size_t)v * H_DIM);
  float4 f = src[threadIdx.x];
  bf16x4 o;
  o.x = (__bf16)f.x; o.y = (__bf16)f.y; o.z = (__bf16)f.z; o.w = (__bf16)f.w;
  ((bf16x4*)X)[(size_t)row * (H_DIM / 4) + threadIdx.x] = o;
}

// ---------------- weight fp32 -> bf16 --------------------------------------
__global__ __launch_bounds__(256) void cvtw_kernel(
    const float* __restrict__ W, bf16_t* __restrict__ Wb)
{
  const size_t i = (size_t)blockIdx.x * 256 + threadIdx.x;  // float4 index
  float4 f = ((const float4*)W)[i];
  bf16x4 o;
  o.x = (__bf16)f.x; o.y = (__bf16)f.y; o.z = (__bf16)f.z; o.w = (__bf16)f.w;
  ((bf16x4*)Wb)[i] = o;
}

// ---------------- GEMM  Y = act(X * W^T + b) -------------------------------
// A: M x K row-major bf16 (X), Bw: N x K row-major bf16 (W), Y: M x N
// act: n<1024 -> tanh (Z), else sigmoid (F,O). m97-style 128x128 tile, BK=32.
template <typename TY>
__global__ __launch_bounds__(256) void gemm_act_kernel(
    const bf16_t* __restrict__ A,
    const bf16_t* __restrict__ Bw,
    const float* __restrict__ bias,
    TY* __restrict__ Y)
{
  constexpr int K = H_DIM;   // 1024
  constexpr int N = N3H;     // 3072
  __shared__ __align__(16) bf16_t As[128 * 32];
  __shared__ __align__(16) bf16_t Bs[128 * 32];

  const int tid  = threadIdx.x;
  const int lane = tid & 63;
  const int wave = tid >> 6;
  const long m0 = (long)blockIdx.y * 128;
  const long n0 = (long)blockIdx.x * 128;

  // staging: thread tid loads 16B -> LDS linear byte offset tid*16 (+4096 for chunk1)
  const int r  = tid >> 2;          // row within 64-row chunk
  const int ck = (tid & 3) * 8;     // k element offset
  const bf16_t* Ag0 = A + (m0 + r) * K + ck;
  const bf16_t* Ag1 = A + (m0 + 64 + r) * K + ck;
  const bf16_t* Bg0 = Bw + (n0 + r) * K + ck;
  const bf16_t* Bg1 = Bw + (n0 + 64 + r) * K + ck;

  bf16_t* Asd0 = As + wave * 512;           // wave-uniform LDS bases (HW adds lane*16B)
  bf16_t* Asd1 = As + 2048 + wave * 512;
  bf16_t* Bsd0 = Bs + wave * 512;
  bf16_t* Bsd1 = Bs + 2048 + wave * 512;

  const int wm = (wave & 1) * 64;
  const int wn = (wave >> 1) * 64;
  const int fr = lane & 15;
  const int quad = lane >> 4;

  ffrag acc[4][4] = {};

  for (int k0 = 0; k0 < K; k0 += 32) {
    __builtin_amdgcn_global_load_lds((AS1 void*)(Ag0 + k0), (AS3 void*)Asd0, 16, 0, 0);
    __builtin_amdgcn_global_load_lds((AS1 void*)(Ag1 + k0), (AS3 void*)Asd1, 16, 0, 0);
    __builtin_amdgcn_global_load_lds((AS1 void*)(Bg0 + k0), (AS3 void*)Bsd0, 16, 0, 0);
    __builtin_amdgcn_global_load_lds((AS1 void*)(Bg1 + k0), (AS3 void*)Bsd1, 16, 0, 0);
    __syncthreads();

    bfrag af[4], bfv[4];
#pragma unroll
    for (int i = 0; i < 4; ++i)
      af[i] = *(const bfrag*)&As[(wm + i * 16 + fr) * 32 + quad * 8];
#pragma unroll
    for (int i = 0; i < 4; ++i)
      bfv[i] = *(const bfrag*)&Bs[(wn + i * 16 + fr) * 32 + quad * 8];
#pragma unroll
    for (int i = 0; i < 4; ++i)
#pragma unroll
      for (int j = 0; j < 4; ++j)
        acc[i][j] = __builtin_amdgcn_mfma_f32_16x16x32_bf16(af[i], bfv[j], acc[i][j], 0, 0, 0);
    __syncthreads();
  }

  // epilogue: D row m = wm+i*16+quad*4+reg, col n = wn+j*16+fr
#pragma unroll
  for (int j = 0; j < 4; ++j) {
    const long n = n0 + wn + j * 16 + fr;
    const float bv = bias[n];
    const bool is_tanh = (n < H_DIM);
#pragma unroll
    for (int i = 0; i < 4; ++i) {
#pragma unroll
      for (int reg = 0; reg < 4; ++reg) {
        const long m = m0 + wm + i * 16 + quad * 4 + reg;
        float y = acc[i][j][reg] + bv;
        float a = is_tanh ? tanh_fast(y) : sigmoidf_(y);
        Y[m * N + n] = (TY)a;
      }
    }
  }
}

// ---------------- sequential scan over S, parallel over (b,h) --------------
// Y holds activated [t=tanh(Z), f=sig(F), o=sig(O)] as (S*B) x 3072.
// c = f*t + (1-f)*c ; out = o*c. 8-deep register prefetch ring.
template <typename TY>
__global__ __launch_bounds__(64) void scan_kernel(
    const TY* __restrict__ Y, bf16_t* __restrict__ Xn,
    float* __restrict__ Out, const int last)
{
  const int t = blockIdx.x * 64 + threadIdx.x;  // 0..16383
  const int b = t >> 10;
  const int h = t & 1023;
  const TY* zp = Y + (size_t)b * N3H + h;
  const long R = (long)B_DIM * N3H;  // 49152
  constexpr int PF = 8;
  float zb[PF], fb[PF], ob[PF];
#pragma unroll
  for (int i = 0; i < PF; ++i) {
    zb[i] = (float)zp[(long)i * R];
    fb[i] = (float)zp[(long)i * R + H_DIM];
    ob[i] = (float)zp[(long)i * R + 2 * H_DIM];
  }
  float c = 0.0f;
  size_t oidx = (size_t)b * H_DIM + h;
  for (int s0 = 0; s0 < S_LEN; s0 += PF) {
#pragma unroll
    for (int k = 0; k < PF; ++k) {
      const int s = s0 + k;
      const float z = zb[k], f = fb[k], o = ob[k];
      const long sp = s + PF;
      if (sp < S_LEN) {
        zb[k] = (float)zp[sp * R];
        fb[k] = (float)zp[sp * R + H_DIM];
        ob[k] = (float)zp[sp * R + 2 * H_DIM];
      }
      c = f * z + (1.0f - f) * c;
      const float val = o * c;
      if (last) {
        if (s < S_LEN - 1) Out[oidx] = val;   // out = X[:-1]
      } else {
        Xn[oidx] = (bf16_t)val;               // next layer's A (bf16)
      }
      oidx += (size_t)B_DIM * H_DIM;
    }
  }
}

extern "C" void kernel_launch(void* const* d_in, const int* in_sizes, int n_in,
                              void* d_out, int out_size, void* d_ws, size_t ws_size,
                              hipStream_t stream)
{
  const int*   x   = (const int*)d_in[0];
  const float* emb = (const float*)d_in[1];
  const float* W[3]  = {(const float*)d_in[2], (const float*)d_in[4], (const float*)d_in[6]};
  const float* bv[3] = {(const float*)d_in[3], (const float*)d_in[5], (const float*)d_in[7]};
  float* out = (float*)d_out;

  char* ws = (char*)d_ws;
  bf16_t* Xbf = (bf16_t*)ws;                           // 32768*1024*2  = 67,108,864 B
  bf16_t* Wbf = (bf16_t*)(ws + 67108864);              // 3*3072*1024*2 = 18,874,368 B
  char*   Yb  = ws + 67108864 + 18874368;              // activation buffer
  const size_t needF32 = 85983232ull + (size_t)M_DIM * N3H * 4;  // ~466 MiB total
  const bool y32 = (ws_size >= needF32);

  for (int l = 0; l < 3; ++l)
    cvtw_kernel<<<3072, 256, 0, stream>>>(W[l], Wbf + (size_t)l * 3145728);
  embed_kernel<<<M_DIM, 256, 0, stream>>>(x, emb, Xbf);

  for (int l = 0; l < 3; ++l) {
    const int last = (l == 2);
    if (y32) {
      gemm_act_kernel<float><<<dim3(24, 256), 256, 0, stream>>>(
          Xbf, Wbf + (size_t)l * 3145728, bv[l], (float*)Yb);
      scan_kernel<float><<<256, 64, 0, stream>>>((const float*)Yb, Xbf, out, last);
    } else {
      gemm_act_kernel<bf16_t><<<dim3(24, 256), 256, 0, stream>>>(
          Xbf, Wbf + (size_t)l * 3145728, bv[l], (bf16_t*)Yb);
      scan_kernel<bf16_t><<<256, 64, 0, stream>>>((const bf16_t*)Yb, Xbf, out, last);
    }
  }
}

// Round 2
// 1744.801 us; speedup vs baseline: 2.6100x; 2.6100x over previous
//
#include <hip/hip_runtime.h>
#include <hip/hip_bf16.h>

#define AS1 __attribute__((address_space(1)))
#define AS3 __attribute__((address_space(3)))

typedef __bf16 bf16_t;
typedef __attribute__((ext_vector_type(8))) __bf16 bfrag;
typedef __attribute__((ext_vector_type(4))) __bf16 bf16x4;
typedef __attribute__((ext_vector_type(4))) float ffrag;

#define S_LEN 2048
#define B_DIM 16
#define H_DIM 1024
#define N3H   3072
#define M_DIM 32768  /* S*B */
#define CHUNK 64
#define NCHUNK 32    /* S_LEN / CHUNK */
#define BH    16384  /* B*H */

__device__ __forceinline__ float sigmoidf_(float x) {
  return 1.0f / (1.0f + __expf(-x));
}
__device__ __forceinline__ float tanh_fast(float x) {
  return 2.0f / (1.0f + __expf(-2.0f * x)) - 1.0f;
}

// ---------------- embedding gather: X[s*B+b][h] = bf16(emb[x[s*B+b]][h]) ---
__global__ __launch_bounds__(256) void embed_kernel(
    const int* __restrict__ x, const float* __restrict__ emb,
    bf16_t* __restrict__ X)
{
  const int row = blockIdx.x;            // 0..32767 = s*16+b
  const int v = x[row];
  const float4* src = (const float4*)(emb + (size_t)v * H_DIM);
  float4 f = src[threadIdx.x];
  bf16x4 o;
  o.x = (__bf16)f.x; o.y = (__bf16)f.y; o.z = (__bf16)f.z; o.w = (__bf16)f.w;
  ((bf16x4*)X)[(size_t)row * (H_DIM / 4) + threadIdx.x] = o;
}

// ---------------- weight fp32 -> bf16 --------------------------------------
__global__ __launch_bounds__(256) void cvtw_kernel(
    const float* __restrict__ W, bf16_t* __restrict__ Wb)
{
  const size_t i = (size_t)blockIdx.x * 256 + threadIdx.x;  // float4 index
  float4 f = ((const float4*)W)[i];
  bf16x4 o;
  o.x = (__bf16)f.x; o.y = (__bf16)f.y; o.z = (__bf16)f.z; o.w = (__bf16)f.w;
  ((bf16x4*)Wb)[i] = o;
}

// ---------------- GEMM  Y = act(X * W^T + b) -------------------------------
// A: M x K row-major bf16 (X), Bw: N x K row-major bf16 (W), Y: M x N fp32
// act: n<1024 -> tanh (Z), else sigmoid (F,O). m97-style 128x128 tile, BK=32.
__global__ __launch_bounds__(256) void gemm_act_kernel(
    const bf16_t* __restrict__ A,
    const bf16_t* __restrict__ Bw,
    const float* __restrict__ bias,
    float* __restrict__ Y)
{
  constexpr int K = H_DIM;   // 1024
  constexpr int N = N3H;     // 3072
  __shared__ __align__(16) bf16_t As[128 * 32];
  __shared__ __align__(16) bf16_t Bs[128 * 32];

  const int tid  = threadIdx.x;
  const int lane = tid & 63;
  const int wave = tid >> 6;
  const long m0 = (long)blockIdx.y * 128;
  const long n0 = (long)blockIdx.x * 128;

  const int r  = tid >> 2;          // row within 64-row chunk
  const int ck = (tid & 3) * 8;     // k element offset
  const bf16_t* Ag0 = A + (m0 + r) * K + ck;
  const bf16_t* Ag1 = A + (m0 + 64 + r) * K + ck;
  const bf16_t* Bg0 = Bw + (n0 + r) * K + ck;
  const bf16_t* Bg1 = Bw + (n0 + 64 + r) * K + ck;

  bf16_t* Asd0 = As + wave * 512;           // wave-uniform LDS bases (HW adds lane*16B)
  bf16_t* Asd1 = As + 2048 + wave * 512;
  bf16_t* Bsd0 = Bs + wave * 512;
  bf16_t* Bsd1 = Bs + 2048 + wave * 512;

  const int wm = (wave & 1) * 64;
  const int wn = (wave >> 1) * 64;
  const int fr = lane & 15;
  const int quad = lane >> 4;

  ffrag acc[4][4] = {};

  for (int k0 = 0; k0 < K; k0 += 32) {
    __builtin_amdgcn_global_load_lds((AS1 void*)(Ag0 + k0), (AS3 void*)Asd0, 16, 0, 0);
    __builtin_amdgcn_global_load_lds((AS1 void*)(Ag1 + k0), (AS3 void*)Asd1, 16, 0, 0);
    __builtin_amdgcn_global_load_lds((AS1 void*)(Bg0 + k0), (AS3 void*)Bsd0, 16, 0, 0);
    __builtin_amdgcn_global_load_lds((AS1 void*)(Bg1 + k0), (AS3 void*)Bsd1, 16, 0, 0);
    __syncthreads();

    bfrag af[4], bfv[4];
#pragma unroll
    for (int i = 0; i < 4; ++i)
      af[i] = *(const bfrag*)&As[(wm + i * 16 + fr) * 32 + quad * 8];
#pragma unroll
    for (int i = 0; i < 4; ++i)
      bfv[i] = *(const bfrag*)&Bs[(wn + i * 16 + fr) * 32 + quad * 8];
#pragma unroll
    for (int i = 0; i < 4; ++i)
#pragma unroll
      for (int j = 0; j < 4; ++j)
        acc[i][j] = __builtin_amdgcn_mfma_f32_16x16x32_bf16(af[i], bfv[j], acc[i][j], 0, 0, 0);
    __syncthreads();
  }

  // epilogue: D row m = wm+i*16+quad*4+reg, col n = wn+j*16+fr
#pragma unroll
  for (int j = 0; j < 4; ++j) {
    const long n = n0 + wn + j * 16 + fr;
    const float bv = bias[n];
    const bool is_tanh = (n < H_DIM);
#pragma unroll
    for (int i = 0; i < 4; ++i) {
#pragma unroll
      for (int reg = 0; reg < 4; ++reg) {
        const long m = m0 + wm + i * 16 + quad * 4 + reg;
        float y = acc[i][j][reg] + bv;
        float a = is_tanh ? tanh_fast(y) : sigmoidf_(y);
        Y[m * N + n] = a;
      }
    }
  }
}

// ---------------- chunked parallel scan ------------------------------------
// c_t = f_t*z_t + (1-f_t)*c_{t-1}.  Linear: c = d + a*c with a=1-f, d=f*z.
// Pass 1: per (chunk g, b, h) compute A=prod(a), D=local scan end (c0=0).
__global__ __launch_bounds__(256) void scan_pass1(
    const float* __restrict__ Y, float* __restrict__ Ag, float* __restrict__ Dg)
{
  const int idx = blockIdx.x * 256 + threadIdx.x;   // g*16384 + b*1024 + h
  const int g = idx >> 14;
  const int b = (idx >> 10) & 15;
  const int h = idx & 1023;
  const float* p = Y + ((size_t)(g * CHUNK * B_DIM + b)) * N3H + h;
  float A = 1.0f, c = 0.0f;
  for (int i = 0; i < CHUNK; ++i) {
    const float z = p[0];
    const float f = p[H_DIM];
    const float a = 1.0f - f;
    c = f * z + a * c;
    A *= a;
    p += (size_t)B_DIM * N3H;
  }
  Ag[idx] = A;
  Dg[idx] = c;
}

// Pass 2: per (b,h) combine chunk summaries sequentially -> chunk start values.
__global__ __launch_bounds__(256) void scan_pass2(
    const float* __restrict__ Ag, const float* __restrict__ Dg,
    float* __restrict__ Cs)
{
  const int j = blockIdx.x * 256 + threadIdx.x;     // 0..16383
  float c = 0.0f;
#pragma unroll
  for (int g = 0; g < NCHUNK; ++g) {
    Cs[g * BH + j] = c;
    c = Dg[g * BH + j] + Ag[g * BH + j] * c;
  }
}

// Pass 3: re-run local scan from the correct start value, emit output.
__global__ __launch_bounds__(256) void scan_pass3(
    const float* __restrict__ Y, const float* __restrict__ Cs,
    bf16_t* __restrict__ Xn, float* __restrict__ Out, const int last)
{
  const int idx = blockIdx.x * 256 + threadIdx.x;
  const int g = idx >> 14;
  const int b = (idx >> 10) & 15;
  const int h = idx & 1023;
  const float* p = Y + ((size_t)(g * CHUNK * B_DIM + b)) * N3H + h;
  float c = Cs[idx];
  size_t oo = (size_t)g * CHUNK * BH + (size_t)b * H_DIM + h;
  for (int i = 0; i < CHUNK; ++i) {
    const float z = p[0];
    const float f = p[H_DIM];
    const float o = p[2 * H_DIM];
    c = f * z + (1.0f - f) * c;
    const float val = o * c;
    if (last) {
      const int s = g * CHUNK + i;
      if (s < S_LEN - 1) Out[oo] = val;   // out = X[:-1]
    } else {
      Xn[oo] = (bf16_t)val;
    }
    p += (size_t)B_DIM * N3H;
    oo += (size_t)BH;
  }
}

extern "C" void kernel_launch(void* const* d_in, const int* in_sizes, int n_in,
                              void* d_out, int out_size, void* d_ws, size_t ws_size,
                              hipStream_t stream)
{
  const int*   x   = (const int*)d_in[0];
  const float* emb = (const float*)d_in[1];
  const float* W[3]  = {(const float*)d_in[2], (const float*)d_in[4], (const float*)d_in[6]};
  const float* bv[3] = {(const float*)d_in[3], (const float*)d_in[5], (const float*)d_in[7]};
  float* out = (float*)d_out;

  char* ws = (char*)d_ws;
  bf16_t* Xbf = (bf16_t*)ws;                                // 67,108,864 B
  bf16_t* Wbf = (bf16_t*)(ws + 67108864);                   //  6,291,456 B (per-layer, reused)
  float*  Yb  = (float*)(ws + 67108864 + 6291456);          // 402,653,184 B
  char* tail  = ws + 67108864 + 6291456 + 402653184;
  float* Ag = (float*)tail;                                 // 2,097,152 B
  float* Dg = (float*)(tail + 2097152);                     // 2,097,152 B
  float* Cs = (float*)(tail + 4194304);                     // 2,097,152 B
  (void)ws_size;

  embed_kernel<<<M_DIM, 256, 0, stream>>>(x, emb, Xbf);

  for (int l = 0; l < 3; ++l) {
    const int last = (l == 2);
    cvtw_kernel<<<1024, 256, 0, stream>>>(W[l], Wbf);
    gemm_act_kernel<<<dim3(24, 256), 256, 0, stream>>>(Xbf, Wbf, bv[l], Yb);
    scan_pass1<<<2048, 256, 0, stream>>>(Yb, Ag, Dg);
    scan_pass2<<<64, 256, 0, stream>>>(Ag, Dg, Cs);
    scan_pass3<<<2048, 256, 0, stream>>>(Yb, Cs, Xbf, out, last);
  }
}

// Round 3
// 1432.172 us; speedup vs baseline: 3.1797x; 1.2183x over previous
//
#include <hip/hip_runtime.h>
#include <hip/hip_bf16.h>

#define AS1 __attribute__((address_space(1)))
#define AS3 __attribute__((address_space(3)))

typedef __bf16 bf16_t;
typedef __attribute__((ext_vector_type(8))) __bf16 bfrag;
typedef __attribute__((ext_vector_type(4))) __bf16 bf16x4;
typedef __attribute__((ext_vector_type(2))) __bf16 bf16x2;
typedef __attribute__((ext_vector_type(4))) float ffrag;

#define S_LEN 2048
#define B_DIM 16
#define H_DIM 1024
#define N3H   3072
#define M_DIM 32768  /* S*B */
#define CHUNK 64
#define NCHUNK 32    /* S_LEN / CHUNK */
#define BH    16384  /* B*H */

__device__ __forceinline__ float sigmoidf_(float x) {
  return 1.0f / (1.0f + __expf(-x));
}
__device__ __forceinline__ float tanh_fast(float x) {
  return 2.0f / (1.0f + __expf(-2.0f * x)) - 1.0f;
}

// ---------------- embedding gather: X[s*B+b][h] = bf16(emb[x[s*B+b]][h]) ---
__global__ __launch_bounds__(256) void embed_kernel(
    const int* __restrict__ x, const float* __restrict__ emb,
    bf16_t* __restrict__ X)
{
  const int row = blockIdx.x;            // 0..32767 = s*16+b
  const int v = x[row];
  const float4* src = (const float4*)(emb + (size_t)v * H_DIM);
  float4 f = src[threadIdx.x];
  bf16x4 o;
  o.x = (__bf16)f.x; o.y = (__bf16)f.y; o.z = (__bf16)f.z; o.w = (__bf16)f.w;
  ((bf16x4*)X)[(size_t)row * (H_DIM / 4) + threadIdx.x] = o;
}

// ---------------- weight fp32 -> bf16 --------------------------------------
// W per layer = 3H*H = 3,145,728 floats = 786,432 float4 -> 3072 blocks.
__global__ __launch_bounds__(256) void cvtw_kernel(
    const float* __restrict__ W, bf16_t* __restrict__ Wb)
{
  const size_t i = (size_t)blockIdx.x * 256 + threadIdx.x;  // float4 index
  float4 f = ((const float4*)W)[i];
  bf16x4 o;
  o.x = (__bf16)f.x; o.y = (__bf16)f.y; o.z = (__bf16)f.z; o.w = (__bf16)f.w;
  ((bf16x4*)Wb)[i] = o;
}

// ---------------- GEMM  Y = act(X * W^T + b) -------------------------------
// A: M x K row-major bf16 (X), Bw: N x K row-major bf16 (W), Y: M x N bf16
// act: n<1024 -> tanh (Z), else sigmoid (F,O). 128x128 tile, BK=32.
// LDS k-chunk slots XOR-swizzled by (row>>1)&3 so fragment ds_read_b128 is
// 2-way-only on banks (free) instead of 8-way.
__global__ __launch_bounds__(256) void gemm_act_kernel(
    const bf16_t* __restrict__ A,
    const bf16_t* __restrict__ Bw,
    const float* __restrict__ bias,
    bf16_t* __restrict__ Y)
{
  constexpr int K = H_DIM;   // 1024
  constexpr int N = N3H;     // 3072
  __shared__ __align__(16) bf16_t As[128 * 32];
  __shared__ __align__(16) bf16_t Bs[128 * 32];

  const int tid  = threadIdx.x;
  const int lane = tid & 63;
  const int wave = tid >> 6;
  const long m0 = (long)blockIdx.y * 128;
  const long n0 = (long)blockIdx.x * 128;

  // staging: thread tid -> LDS row r = tid>>2, slot s4 = tid&3.
  // slot s4 holds global k-chunk (s4 ^ ((r>>1)&3))  [swizzle]
  const int r  = tid >> 2;
  const int s4 = tid & 3;
  const int ck = (s4 ^ ((r >> 1) & 3)) * 8;   // k element offset of staged chunk
  const bf16_t* Ag0 = A + (m0 + r) * K + ck;
  const bf16_t* Ag1 = A + (m0 + 64 + r) * K + ck;
  const bf16_t* Bg0 = Bw + (n0 + r) * K + ck;
  const bf16_t* Bg1 = Bw + (n0 + 64 + r) * K + ck;

  bf16_t* Asd0 = As + wave * 512;           // wave-uniform LDS bases (HW adds lane*16B)
  bf16_t* Asd1 = As + 2048 + wave * 512;
  bf16_t* Bsd0 = Bs + wave * 512;
  bf16_t* Bsd1 = Bs + 2048 + wave * 512;

  const int wm = (wave & 1) * 64;
  const int wn = (wave >> 1) * 64;
  const int fr = lane & 15;
  const int quad = lane >> 4;
  const int so = (quad ^ ((fr >> 1) & 3)) * 8;   // swizzled slot offset for reads

  ffrag acc[4][4] = {};

  for (int k0 = 0; k0 < K; k0 += 32) {
    __builtin_amdgcn_global_load_lds((AS1 void*)(Ag0 + k0), (AS3 void*)Asd0, 16, 0, 0);
    __builtin_amdgcn_global_load_lds((AS1 void*)(Ag1 + k0), (AS3 void*)Asd1, 16, 0, 0);
    __builtin_amdgcn_global_load_lds((AS1 void*)(Bg0 + k0), (AS3 void*)Bsd0, 16, 0, 0);
    __builtin_amdgcn_global_load_lds((AS1 void*)(Bg1 + k0), (AS3 void*)Bsd1, 16, 0, 0);
    __syncthreads();

    bfrag af[4], bfv[4];
#pragma unroll
    for (int i = 0; i < 4; ++i)
      af[i] = *(const bfrag*)&As[(wm + i * 16 + fr) * 32 + so];
#pragma unroll
    for (int i = 0; i < 4; ++i)
      bfv[i] = *(const bfrag*)&Bs[(wn + i * 16 + fr) * 32 + so];
#pragma unroll
    for (int i = 0; i < 4; ++i)
#pragma unroll
      for (int j = 0; j < 4; ++j)
        acc[i][j] = __builtin_amdgcn_mfma_f32_16x16x32_bf16(af[i], bfv[j], acc[i][j], 0, 0, 0);
    __syncthreads();
  }

  // epilogue: D row m = wm+i*16+quad*4+reg, col n = wn+j*16+fr
#pragma unroll
  for (int j = 0; j < 4; ++j) {
    const long n = n0 + wn + j * 16 + fr;
    const float bv = bias[n];
    const bool is_tanh = (n < H_DIM);
#pragma unroll
    for (int i = 0; i < 4; ++i) {
#pragma unroll
      for (int reg = 0; reg < 4; ++reg) {
        const long m = m0 + wm + i * 16 + quad * 4 + reg;
        float y = acc[i][j][reg] + bv;
        float a = is_tanh ? tanh_fast(y) : sigmoidf_(y);
        Y[m * N + n] = (bf16_t)a;
      }
    }
  }
}

// ---------------- chunked parallel scan (bf16 Y, 2-wide vectorized) --------
// c_t = f_t*z_t + (1-f_t)*c_{t-1}.  Linear: c = d + a*c with a=1-f, d=f*z.
// Pass 1: per (chunk g, b, h-pair) compute A=prod(a), D=local scan end (c0=0).
__global__ __launch_bounds__(256) void scan_pass1(
    const bf16_t* __restrict__ Y, float* __restrict__ Ag, float* __restrict__ Dg)
{
  const int idx = blockIdx.x * 256 + threadIdx.x;   // g*8192 + b*512 + h2
  const int g = idx >> 13;
  const int b = (idx >> 9) & 15;
  const int h2 = idx & 511;
  const bf16_t* p = Y + ((size_t)(g * CHUNK * B_DIM + b)) * N3H + h2 * 2;
  float A0 = 1.0f, A1 = 1.0f, c0 = 0.0f, c1 = 0.0f;
  for (int i = 0; i < CHUNK; ++i) {
    const bf16x2 zv = *(const bf16x2*)(p);
    const bf16x2 fv = *(const bf16x2*)(p + H_DIM);
    const float f0 = (float)fv[0], f1 = (float)fv[1];
    const float a0 = 1.0f - f0,    a1 = 1.0f - f1;
    c0 = f0 * (float)zv[0] + a0 * c0;
    c1 = f1 * (float)zv[1] + a1 * c1;
    A0 *= a0;
    A1 *= a1;
    p += (size_t)B_DIM * N3H;
  }
  const int base = g * BH + b * H_DIM + h2 * 2;
  *(float2*)(Ag + base) = make_float2(A0, A1);
  *(float2*)(Dg + base) = make_float2(c0, c1);
}

// Pass 2: per (b,h) combine chunk summaries sequentially -> chunk start values.
__global__ __launch_bounds__(256) void scan_pass2(
    const float* __restrict__ Ag, const float* __restrict__ Dg,
    float* __restrict__ Cs)
{
  const int j = blockIdx.x * 256 + threadIdx.x;     // 0..16383
  float c = 0.0f;
#pragma unroll
  for (int g = 0; g < NCHUNK; ++g) {
    Cs[g * BH + j] = c;
    c = Dg[g * BH + j] + Ag[g * BH + j] * c;
  }
}

// Pass 3: re-run local scan from the correct start value, emit output.
__global__ __launch_bounds__(256) void scan_pass3(
    const bf16_t* __restrict__ Y, const float* __restrict__ Cs,
    bf16_t* __restrict__ Xn, float* __restrict__ Out, const int last)
{
  const int idx = blockIdx.x * 256 + threadIdx.x;   // g*8192 + b*512 + h2
  const int g = idx >> 13;
  const int b = (idx >> 9) & 15;
  const int h2 = idx & 511;
  const bf16_t* p = Y + ((size_t)(g * CHUNK * B_DIM + b)) * N3H + h2 * 2;
  const int cb = g * BH + b * H_DIM + h2 * 2;
  float c0 = Cs[cb], c1 = Cs[cb + 1];
  size_t oo = (size_t)g * CHUNK * BH + (size_t)b * H_DIM + h2 * 2;
  for (int i = 0; i < CHUNK; ++i) {
    const bf16x2 zv = *(const bf16x2*)(p);
    const bf16x2 fv = *(const bf16x2*)(p + H_DIM);
    const bf16x2 ov = *(const bf16x2*)(p + 2 * H_DIM);
    const float f0 = (float)fv[0], f1 = (float)fv[1];
    c0 = f0 * (float)zv[0] + (1.0f - f0) * c0;
    c1 = f1 * (float)zv[1] + (1.0f - f1) * c1;
    const float v0 = (float)ov[0] * c0;
    const float v1 = (float)ov[1] * c1;
    if (last) {
      const int s = g * CHUNK + i;
      if (s < S_LEN - 1) *(float2*)(Out + oo) = make_float2(v0, v1);  // out = X[:-1]
    } else {
      bf16x2 w; w[0] = (__bf16)v0; w[1] = (__bf16)v1;
      *(bf16x2*)(Xn + oo) = w;
    }
    p += (size_t)B_DIM * N3H;
    oo += (size_t)BH;
  }
}

extern "C" void kernel_launch(void* const* d_in, const int* in_sizes, int n_in,
                              void* d_out, int out_size, void* d_ws, size_t ws_size,
                              hipStream_t stream)
{
  const int*   x   = (const int*)d_in[0];
  const float* emb = (const float*)d_in[1];
  const float* W[3]  = {(const float*)d_in[2], (const float*)d_in[4], (const float*)d_in[6]};
  const float* bv[3] = {(const float*)d_in[3], (const float*)d_in[5], (const float*)d_in[7]};
  float* out = (float*)d_out;

  char* ws = (char*)d_ws;
  bf16_t* Xbf = (bf16_t*)ws;                                // 67,108,864 B
  bf16_t* Wbf = (bf16_t*)(ws + 67108864);                   //  6,291,456 B (per-layer, reused)
  bf16_t* Yb  = (bf16_t*)(ws + 67108864 + 6291456);         // 201,326,592 B (bf16 Y)
  char* tail  = ws + 67108864 + 6291456 + 201326592;
  float* Ag = (float*)tail;                                 // 2,097,152 B
  float* Dg = (float*)(tail + 2097152);                     // 2,097,152 B
  float* Cs = (float*)(tail + 4194304);                     // 2,097,152 B
  (void)ws_size;

  embed_kernel<<<M_DIM, 256, 0, stream>>>(x, emb, Xbf);

  for (int l = 0; l < 3; ++l) {
    const int last = (l == 2);
    cvtw_kernel<<<3072, 256, 0, stream>>>(W[l], Wbf);
    gemm_act_kernel<<<dim3(24, 256), 256, 0, stream>>>(Xbf, Wbf, bv[l], Yb);
    scan_pass1<<<1024, 256, 0, stream>>>(Yb, Ag, Dg);
    scan_pass2<<<64, 256, 0, stream>>>(Ag, Dg, Cs);
    scan_pass3<<<1024, 256, 0, stream>>>(Yb, Cs, Xbf, out, last);
  }
}